// Round 1
// baseline (197.229 us; speedup 1.0000x reference)
//
#include <hip/hip_runtime.h>
#include <hip/hip_fp16.h>

#define HID 512
#define NH 8
#define VD 64
#define SEQ 2048
#define NB 2
#define MTOT (NB*SEQ)          // 4096
#define LOG2E 1.4426950408889634f

typedef _Float16 f16x8 __attribute__((ext_vector_type(8)));
typedef _Float16 f16x4 __attribute__((ext_vector_type(4)));
typedef float f32x4 __attribute__((ext_vector_type(4)));

// ---- workspace layout (bytes) ----
#define OFF_SEQH  (0u)
#define SZ_SEQH   ((unsigned)(MTOT*HID*2))            // 4 MB
#define OFF_WT    (OFF_SEQH + SZ_SEQH)
#define SZ_WT     ((unsigned)(3*NH*VD*HID*2))         // 1.5 MB  [z][h][vd][k]
#define OFF_WOT   (OFF_WT + SZ_WT)
#define SZ_WOT    ((unsigned)(HID*HID*2))             // 0.5 MB  [n][k]
#define OFF_BIAS  (OFF_WOT + SZ_WOT)
#define SZ_BIAS   ((unsigned)(3*NH*VD*4))             // fp32 [z][h][vd]
#define OFF_Q     (OFF_BIAS + SZ_BIAS)
#define SZ_QKV    ((unsigned)(NB*NH*SEQ*VD*2))        // 4 MB each
#define OFF_K     (OFF_Q + SZ_QKV)
#define OFF_VT    (OFF_K + SZ_QKV)                    // V transposed [b][h][vd][s]
#define OFF_Z     (OFF_VT + SZ_QKV)                   // [b][s][h*vd] f16

// XOR swizzle: row-major tiles with 128B rows; granule g (16B) -> g ^ (row&7)
__device__ __forceinline__ int swz(int row, int g) {
    return row*128 + ((g ^ (row & 7)) << 4);
}

// ---------------- kernel 1: convert / pack ----------------
__global__ __launch_bounds__(256) void k_convert(
    const float* __restrict__ seq,
    const float* __restrict__ Wq, const float* __restrict__ bq,
    const float* __restrict__ Wk, const float* __restrict__ bk,
    const float* __restrict__ Wv, const float* __restrict__ bv,
    const float* __restrict__ Wo, char* __restrict__ ws)
{
    int tid = blockIdx.x*256 + threadIdx.x;
    int nt  = gridDim.x*256;

    _Float16* seqh = (_Float16*)(ws + OFF_SEQH);
    for (int i = tid; i < MTOT*HID/4; i += nt) {
        float4 v = ((const float4*)seq)[i];
        f16x4 o = { (_Float16)v.x, (_Float16)v.y, (_Float16)v.z, (_Float16)v.w };
        ((f16x4*)seqh)[i] = o;
    }

    _Float16* wt = (_Float16*)(ws + OFF_WT);   // [z][h][vd][k]
    for (int i = tid; i < 3*NH*VD*HID; i += nt) {
        int k = i & (HID-1); int t = i >> 9;
        int vd = t & (VD-1); t >>= 6;
        int h = t & (NH-1);  int z = t >> 3;
        const float* W = (z==0) ? Wq : (z==1 ? Wk : Wv);
        wt[i] = (_Float16)W[(h*HID + k)*VD + vd];
    }

    _Float16* wot = (_Float16*)(ws + OFF_WOT); // [n][k]
    for (int i = tid; i < HID*HID; i += nt) {
        int k = i & (HID-1); int n = i >> 9;
        wot[i] = (_Float16)Wo[k*HID + n];
    }

    float* bias = (float*)(ws + OFF_BIAS);     // [z][h][vd] fp32
    for (int i = tid; i < 3*NH*VD; i += nt) {
        int z = i / (NH*VD); int r = i % (NH*VD);
        const float* b = (z==0) ? bq : (z==1 ? bk : bv);
        bias[i] = b[r];
    }
}

// ---------------- kernel 2: QKV projection GEMM ----------------
// grid (32, 8, 3): 128-row M tile, head, z in {Q,K,V}. block 256 (4 waves).
// C[128 x 64] = seqh[128 x 512] * W^T[z][h]  (+bias). V is written transposed.
__global__ __launch_bounds__(256) void k_proj(char* __restrict__ ws)
{
    __shared__ uint4 smem4[1536];   // 24 KB: A tile 16KB + B tile 8KB
    char* smem = (char*)smem4;
    const _Float16* seqh = (const _Float16*)(ws + OFF_SEQH);
    const _Float16* wt   = (const _Float16*)(ws + OFF_WT);
    const float*    bias = (const float*)(ws + OFF_BIAS);

    int m0 = blockIdx.x * 128;
    int h  = blockIdx.y;
    int z  = blockIdx.z;
    int tid = threadIdx.x, lane = tid & 63, w = tid >> 6;

    f32x4 acc[2][4] = {};

    for (int kt = 0; kt < HID/64; ++kt) {
        // stage A: 128 rows x 64 cols f16 (swizzled)
        #pragma unroll
        for (int p = 0; p < 4; ++p) {
            int flat = p*256 + tid; int row = flat >> 3, g = flat & 7;
            uint4 v = *(const uint4*)(seqh + (m0+row)*HID + kt*64 + g*8);
            *(uint4*)(smem + swz(row, g)) = v;
        }
        // stage B^T: 64 rows(n) x 64 cols(k)
        #pragma unroll
        for (int p = 0; p < 2; ++p) {
            int flat = p*256 + tid; int n = flat >> 3, g = flat & 7;
            uint4 v = *(const uint4*)(wt + ((z*NH+h)*VD + n)*HID + kt*64 + g*8);
            *(uint4*)(smem + 16384 + swz(n, g)) = v;
        }
        __syncthreads();
        #pragma unroll
        for (int kf = 0; kf < 2; ++kf) {
            f16x8 a[2], b[4];
            #pragma unroll
            for (int mf = 0; mf < 2; ++mf) {
                int row = w*32 + mf*16 + (lane & 15);
                a[mf] = *(const f16x8*)(smem + swz(row, kf*4 + (lane>>4)));
            }
            #pragma unroll
            for (int nf = 0; nf < 4; ++nf) {
                int n = nf*16 + (lane & 15);
                b[nf] = *(const f16x8*)(smem + 16384 + swz(n, kf*4 + (lane>>4)));
            }
            #pragma unroll
            for (int mf = 0; mf < 2; ++mf)
                #pragma unroll
                for (int nf = 0; nf < 4; ++nf)
                    acc[mf][nf] = __builtin_amdgcn_mfma_f32_16x16x32_f16(
                        a[mf], b[nf], acc[mf][nf], 0, 0, 0);
        }
        __syncthreads();
    }

    int bb = m0 >> 11;          // batch (128 | 2048)
    int s0 = m0 & (SEQ-1);

    if (z < 2) {
        _Float16* out = (_Float16*)(ws + (z==0 ? OFF_Q : OFF_K));
        #pragma unroll
        for (int mf = 0; mf < 2; ++mf)
            #pragma unroll
            for (int nf = 0; nf < 4; ++nf)
                #pragma unroll
                for (int r = 0; r < 4; ++r) {
                    int mrow = w*32 + mf*16 + ((lane>>4)<<2) + r;
                    int col  = nf*16 + (lane & 15);
                    float v = acc[mf][nf][r] + bias[(z*NH+h)*VD + col];
                    out[((bb*NH+h)*SEQ + s0 + mrow)*VD + col] = (_Float16)v;
                }
    } else {
        // V: transpose 128x64 -> 64x128 through LDS, then coalesced store
        _Float16* sT = (_Float16*)smem;  // [64][128]
        #pragma unroll
        for (int mf = 0; mf < 2; ++mf)
            #pragma unroll
            for (int nf = 0; nf < 4; ++nf)
                #pragma unroll
                for (int r = 0; r < 4; ++r) {
                    int srow = w*32 + mf*16 + ((lane>>4)<<2) + r;
                    int vd   = nf*16 + (lane & 15);
                    float v = acc[mf][nf][r] + bias[(z*NH+h)*VD + vd];
                    sT[vd*128 + srow] = (_Float16)v;
                }
        __syncthreads();
        _Float16* vt = (_Float16*)(ws + OFF_VT);
        #pragma unroll
        for (int p = 0; p < 4; ++p) {
            int flat = p*256 + tid; int vd = flat >> 4, g = flat & 15;
            uint4 v = *(const uint4*)((char*)sT + vd*256 + g*16);
            *(uint4*)(vt + ((bb*NH+h)*VD + vd)*SEQ + s0 + g*8) = v;
        }
    }
}

// ---------------- kernel 3: flash attention ----------------
// grid (16, 16): (S/128 q-tiles, b*H). block 256 (4 waves, 32 q-rows each).
__global__ __launch_bounds__(256) void k_attn(char* __restrict__ ws)
{
    __shared__ uint4 smem4[3072];   // 48 KB: Q 16K | K 8K | Vt 8K | P 16K
    char* smem = (char*)smem4;
    const int OQ = 0, OK = 16384, OV = 24576, OP = 32768;

    int m0 = blockIdx.x * 128;
    int bh = blockIdx.y;
    int tid = threadIdx.x, lane = tid & 63, w = tid >> 6;

    const _Float16* Qb  = (const _Float16*)(ws + OFF_Q)  + (unsigned)bh*SEQ*VD;
    const _Float16* Kb  = (const _Float16*)(ws + OFF_K)  + (unsigned)bh*SEQ*VD;
    const _Float16* Vtb = (const _Float16*)(ws + OFF_VT) + (unsigned)bh*VD*SEQ;
    _Float16* Zp = (_Float16*)(ws + OFF_Z);

    // load Q tile, hoist fragments to registers
    #pragma unroll
    for (int p = 0; p < 4; ++p) {
        int flat = p*256 + tid; int row = flat >> 3, g = flat & 7;
        uint4 v = *(const uint4*)(Qb + (m0+row)*VD + g*8);
        *(uint4*)(smem + OQ + swz(row, g)) = v;
    }
    __syncthreads();
    f16x8 aq[2][2];
    #pragma unroll
    for (int mf = 0; mf < 2; ++mf)
        #pragma unroll
        for (int kf = 0; kf < 2; ++kf) {
            int row = w*32 + mf*16 + (lane & 15);
            aq[mf][kf] = *(const f16x8*)(smem + OQ + swz(row, kf*4 + (lane>>4)));
        }

    float mrun[2][4], lrun[2][4];
    f32x4 zacc[2][4] = {};
    #pragma unroll
    for (int mf = 0; mf < 2; ++mf)
        #pragma unroll
        for (int r = 0; r < 4; ++r) { mrun[mf][r] = -INFINITY; lrun[mf][r] = 0.f; }

    for (int t0 = 0; t0 < SEQ; t0 += 64) {
        // stage K [64][64] and Vt [64][64]
        #pragma unroll
        for (int p = 0; p < 2; ++p) {
            int flat = p*256 + tid; int r = flat >> 3, g = flat & 7;
            uint4 v = *(const uint4*)(Kb + (t0+r)*VD + g*8);
            *(uint4*)(smem + OK + swz(r, g)) = v;
        }
        #pragma unroll
        for (int p = 0; p < 2; ++p) {
            int flat = p*256 + tid; int r = flat >> 3, g = flat & 7;
            uint4 v = *(const uint4*)(Vtb + r*SEQ + t0 + g*8);
            *(uint4*)(smem + OV + swz(r, g)) = v;
        }
        __syncthreads();

        // QK^T
        f32x4 sacc[2][4] = {};
        #pragma unroll
        for (int kf = 0; kf < 2; ++kf) {
            f16x8 bk_[4];
            #pragma unroll
            for (int nf = 0; nf < 4; ++nf) {
                int trow = nf*16 + (lane & 15);
                bk_[nf] = *(const f16x8*)(smem + OK + swz(trow, kf*4 + (lane>>4)));
            }
            #pragma unroll
            for (int mf = 0; mf < 2; ++mf)
                #pragma unroll
                for (int nf = 0; nf < 4; ++nf)
                    sacc[mf][nf] = __builtin_amdgcn_mfma_f32_16x16x32_f16(
                        aq[mf][kf], bk_[nf], sacc[mf][nf], 0, 0, 0);
        }

        // online softmax (rows live on lanes sharing lane>>4; reduce over lane&15)
        #pragma unroll
        for (int mf = 0; mf < 2; ++mf) {
            float mn[4], al[4];
            #pragma unroll
            for (int r = 0; r < 4; ++r) {
                float v = fmaxf(fmaxf(sacc[mf][0][r], sacc[mf][1][r]),
                                fmaxf(sacc[mf][2][r], sacc[mf][3][r]));
                #pragma unroll
                for (int d = 1; d < 16; d <<= 1) v = fmaxf(v, __shfl_xor(v, d, 64));
                float lm = v * 0.125f;
                mn[r] = fmaxf(mrun[mf][r], lm);
                al[r] = exp2f((mrun[mf][r] - mn[r]) * LOG2E);
                mrun[mf][r] = mn[r];
            }
            #pragma unroll
            for (int r = 0; r < 4; ++r) {
                float s = 0.f;
                #pragma unroll
                for (int nf = 0; nf < 4; ++nf) {
                    float pv = exp2f((sacc[mf][nf][r]*0.125f - mn[r]) * LOG2E);
                    sacc[mf][nf][r] = pv;
                    s += pv;
                }
                #pragma unroll
                for (int d = 1; d < 16; d <<= 1) s += __shfl_xor(s, d, 64);
                lrun[mf][r] = lrun[mf][r]*al[r] + s;
                #pragma unroll
                for (int nf = 0; nf < 4; ++nf) zacc[mf][nf][r] *= al[r];
            }
            // write P tile (f16, swizzled)
            #pragma unroll
            for (int nf = 0; nf < 4; ++nf)
                #pragma unroll
                for (int r = 0; r < 4; ++r) {
                    int row = w*32 + mf*16 + ((lane>>4)<<2) + r;
                    int gb  = (nf*2 + ((lane>>3)&1)) ^ (row & 7);
                    *(_Float16*)(smem + OP + row*128 + gb*16 + (lane&7)*2) =
                        (_Float16)sacc[mf][nf][r];
                }
        }
        __syncthreads();

        // PV: zacc += P[128x64] * V[64x64]  (B^T = Vt rows)
        #pragma unroll
        for (int kf = 0; kf < 2; ++kf) {
            f16x8 ap[2], bv_[4];
            #pragma unroll
            for (int mf = 0; mf < 2; ++mf) {
                int row = w*32 + mf*16 + (lane & 15);
                ap[mf] = *(const f16x8*)(smem + OP + swz(row, kf*4 + (lane>>4)));
            }
            #pragma unroll
            for (int nf = 0; nf < 4; ++nf) {
                int vd = nf*16 + (lane & 15);
                bv_[nf] = *(const f16x8*)(smem + OV + swz(vd, kf*4 + (lane>>4)));
            }
            #pragma unroll
            for (int mf = 0; mf < 2; ++mf)
                #pragma unroll
                for (int nf = 0; nf < 4; ++nf)
                    zacc[mf][nf] = __builtin_amdgcn_mfma_f32_16x16x32_f16(
                        ap[mf], bv_[nf], zacc[mf][nf], 0, 0, 0);
        }
        __syncthreads();   // protect K/Vt/P before next tile's staging
    }

    // epilogue: Z[b][s][h*64+vd] f16
    int bb = bh >> 3, h = bh & 7;
    #pragma unroll
    for (int mf = 0; mf < 2; ++mf)
        #pragma unroll
        for (int nf = 0; nf < 4; ++nf)
            #pragma unroll
            for (int r = 0; r < 4; ++r) {
                int s  = m0 + w*32 + mf*16 + ((lane>>4)<<2) + r;
                int vd = nf*16 + (lane & 15);
                float v = zacc[mf][nf][r] / lrun[mf][r];
                Zp[((unsigned)(bb*SEQ + s))*HID + h*VD + vd] = (_Float16)v;
            }
}

// ---------------- kernel 4: output projection ----------------
// grid (32, 8): [4096 x 512] = Z[4096 x 512] * Wo  (+bo), fp32 out
__global__ __launch_bounds__(256) void k_outproj(const char* __restrict__ ws,
                                                 const float* __restrict__ bo,
                                                 float* __restrict__ out)
{
    __shared__ uint4 smem4[1536];
    char* smem = (char*)smem4;
    const _Float16* Zp  = (const _Float16*)(ws + OFF_Z);
    const _Float16* wot = (const _Float16*)(ws + OFF_WOT);

    int m0 = blockIdx.x * 128;
    int n0 = blockIdx.y * 64;
    int tid = threadIdx.x, lane = tid & 63, w = tid >> 6;

    f32x4 acc[2][4] = {};

    for (int kt = 0; kt < HID/64; ++kt) {
        #pragma unroll
        for (int p = 0; p < 4; ++p) {
            int flat = p*256 + tid; int row = flat >> 3, g = flat & 7;
            uint4 v = *(const uint4*)(Zp + (m0+row)*HID + kt*64 + g*8);
            *(uint4*)(smem + swz(row, g)) = v;
        }
        #pragma unroll
        for (int p = 0; p < 2; ++p) {
            int flat = p*256 + tid; int n = flat >> 3, g = flat & 7;
            uint4 v = *(const uint4*)(wot + (n0+n)*HID + kt*64 + g*8);
            *(uint4*)(smem + 16384 + swz(n, g)) = v;
        }
        __syncthreads();
        #pragma unroll
        for (int kf = 0; kf < 2; ++kf) {
            f16x8 a[2], b[4];
            #pragma unroll
            for (int mf = 0; mf < 2; ++mf) {
                int row = w*32 + mf*16 + (lane & 15);
                a[mf] = *(const f16x8*)(smem + swz(row, kf*4 + (lane>>4)));
            }
            #pragma unroll
            for (int nf = 0; nf < 4; ++nf) {
                int n = nf*16 + (lane & 15);
                b[nf] = *(const f16x8*)(smem + 16384 + swz(n, kf*4 + (lane>>4)));
            }
            #pragma unroll
            for (int mf = 0; mf < 2; ++mf)
                #pragma unroll
                for (int nf = 0; nf < 4; ++nf)
                    acc[mf][nf] = __builtin_amdgcn_mfma_f32_16x16x32_f16(
                        a[mf], b[nf], acc[mf][nf], 0, 0, 0);
        }
        __syncthreads();
    }

    #pragma unroll
    for (int mf = 0; mf < 2; ++mf)
        #pragma unroll
        for (int nf = 0; nf < 4; ++nf)
            #pragma unroll
            for (int r = 0; r < 4; ++r) {
                int mrow = m0 + w*32 + mf*16 + ((lane>>4)<<2) + r;
                int col  = n0 + nf*16 + (lane & 15);
                out[(unsigned)mrow*HID + col] = acc[mf][nf][r] + bo[col];
            }
}

extern "C" void kernel_launch(void* const* d_in, const int* in_sizes, int n_in,
                              void* d_out, int out_size, void* d_ws, size_t ws_size,
                              hipStream_t stream)
{
    const float* seq = (const float*)d_in[0];
    const float* Wq  = (const float*)d_in[1];
    const float* bq  = (const float*)d_in[2];
    const float* Wk  = (const float*)d_in[3];
    const float* bk  = (const float*)d_in[4];
    const float* Wv  = (const float*)d_in[5];
    const float* bv  = (const float*)d_in[6];
    const float* Wo  = (const float*)d_in[7];
    const float* bo  = (const float*)d_in[8];
    char* ws = (char*)d_ws;
    float* out = (float*)d_out;

    k_convert<<<dim3(512), dim3(256), 0, stream>>>(seq, Wq, bq, Wk, bk, Wv, bv, Wo, ws);
    k_proj<<<dim3(32, 8, 3), dim3(256), 0, stream>>>(ws);
    k_attn<<<dim3(16, 16), dim3(256), 0, stream>>>(ws);
    k_outproj<<<dim3(32, 8), dim3(256), 0, stream>>>(ws, bo, out);
}

// Round 2
// 153.132 us; speedup vs baseline: 1.2880x; 1.2880x over previous
//
#include <hip/hip_runtime.h>
#include <hip/hip_fp16.h>

#define HID 512
#define NH 8
#define VD 64
#define SEQ 2048
#define NB 2
#define MTOT (NB*SEQ)          // 4096
#define LOG2E 1.4426950408889634f
#define QSCALE (0.125f * LOG2E)   // fold softmax scale + log2e into Q

typedef _Float16 f16x8 __attribute__((ext_vector_type(8)));
typedef _Float16 f16x4 __attribute__((ext_vector_type(4)));
typedef float f32x4 __attribute__((ext_vector_type(4)));

// ---- workspace layout (bytes) ----
#define OFF_SEQH  (0u)
#define SZ_SEQH   ((unsigned)(MTOT*HID*2))            // 4 MB
#define OFF_WT    (OFF_SEQH + SZ_SEQH)
#define SZ_WT     ((unsigned)(3*NH*VD*HID*2))         // 1.5 MB  [z][h][vd][k]
#define OFF_WOT   (OFF_WT + SZ_WT)
#define SZ_WOT    ((unsigned)(HID*HID*2))             // 0.5 MB  [n][k]
#define OFF_BIAS  (OFF_WOT + SZ_WOT)
#define SZ_BIAS   ((unsigned)(3*NH*VD*4))             // fp32 [z][h][vd]
#define OFF_Q     (OFF_BIAS + SZ_BIAS)
#define SZ_QKV    ((unsigned)(NB*NH*SEQ*VD*2))        // 4 MB each
#define OFF_K     (OFF_Q + SZ_QKV)
#define OFF_VT    (OFF_K + SZ_QKV)                    // V transposed [b][h][vd][s]
#define OFF_Z     (OFF_VT + SZ_QKV)                   // [b][s][h*vd] f16

// XOR swizzle for 128B rows (8 granules of 16B)
__device__ __forceinline__ int swz(int row, int g) {
    return row*128 + ((g ^ (row & 7)) << 4);
}
// XOR swizzle for 256B rows (16 granules of 16B); XOR touches low 3 bits only
__device__ __forceinline__ int swz256(int row, int g) {
    return row*256 + ((g ^ (row & 7)) << 4);
}

// ---------------- kernel 1: convert / pack ----------------
__global__ __launch_bounds__(256) void k_convert(
    const float* __restrict__ seq,
    const float* __restrict__ Wq, const float* __restrict__ bq,
    const float* __restrict__ Wk, const float* __restrict__ bk,
    const float* __restrict__ Wv, const float* __restrict__ bv,
    const float* __restrict__ Wo, char* __restrict__ ws)
{
    int tid = blockIdx.x*256 + threadIdx.x;
    int nt  = gridDim.x*256;

    _Float16* seqh = (_Float16*)(ws + OFF_SEQH);
    for (int i = tid; i < MTOT*HID/4; i += nt) {
        float4 v = ((const float4*)seq)[i];
        f16x4 o = { (_Float16)v.x, (_Float16)v.y, (_Float16)v.z, (_Float16)v.w };
        ((f16x4*)seqh)[i] = o;
    }

    _Float16* wt = (_Float16*)(ws + OFF_WT);   // [z][h][vd][k]
    for (int i = tid; i < 3*NH*VD*HID; i += nt) {
        int k = i & (HID-1); int t = i >> 9;
        int vd = t & (VD-1); t >>= 6;
        int h = t & (NH-1);  int z = t >> 3;
        const float* W = (z==0) ? Wq : (z==1 ? Wk : Wv);
        wt[i] = (_Float16)W[(h*HID + k)*VD + vd];
    }

    _Float16* wot = (_Float16*)(ws + OFF_WOT); // [n][k]
    for (int i = tid; i < HID*HID; i += nt) {
        int k = i & (HID-1); int n = i >> 9;
        wot[i] = (_Float16)Wo[k*HID + n];
    }

    float* bias = (float*)(ws + OFF_BIAS);     // [z][h][vd] fp32
    for (int i = tid; i < 3*NH*VD; i += nt) {
        int z = i / (NH*VD); int r = i % (NH*VD);
        const float* b = (z==0) ? bq : (z==1 ? bk : bv);
        bias[i] = b[r];
    }
}

// ---------------- kernel 2: QKV projection GEMM ----------------
// grid (32, 8, 3): 128-row M tile, head, z in {Q,K,V}. block 256 (4 waves).
// C[128 x 64] = seqh[128 x 512] * W^T[z][h]  (+bias). V is written transposed.
// Q is pre-scaled by QSCALE so attention scores are directly in exp2 domain.
__global__ __launch_bounds__(256) void k_proj(char* __restrict__ ws)
{
    __shared__ uint4 smem4[1536];   // 24 KB: A tile 16KB + B tile 8KB
    char* smem = (char*)smem4;
    const _Float16* seqh = (const _Float16*)(ws + OFF_SEQH);
    const _Float16* wt   = (const _Float16*)(ws + OFF_WT);
    const float*    bias = (const float*)(ws + OFF_BIAS);

    int m0 = blockIdx.x * 128;
    int h  = blockIdx.y;
    int z  = blockIdx.z;
    int tid = threadIdx.x, lane = tid & 63, w = tid >> 6;

    f32x4 acc[2][4] = {};

    for (int kt = 0; kt < HID/64; ++kt) {
        #pragma unroll
        for (int p = 0; p < 4; ++p) {
            int flat = p*256 + tid; int row = flat >> 3, g = flat & 7;
            uint4 v = *(const uint4*)(seqh + (m0+row)*HID + kt*64 + g*8);
            *(uint4*)(smem + swz(row, g)) = v;
        }
        #pragma unroll
        for (int p = 0; p < 2; ++p) {
            int flat = p*256 + tid; int n = flat >> 3, g = flat & 7;
            uint4 v = *(const uint4*)(wt + ((z*NH+h)*VD + n)*HID + kt*64 + g*8);
            *(uint4*)(smem + 16384 + swz(n, g)) = v;
        }
        __syncthreads();
        #pragma unroll
        for (int kf = 0; kf < 2; ++kf) {
            f16x8 a[2], b[4];
            #pragma unroll
            for (int mf = 0; mf < 2; ++mf) {
                int row = w*32 + mf*16 + (lane & 15);
                a[mf] = *(const f16x8*)(smem + swz(row, kf*4 + (lane>>4)));
            }
            #pragma unroll
            for (int nf = 0; nf < 4; ++nf) {
                int n = nf*16 + (lane & 15);
                b[nf] = *(const f16x8*)(smem + 16384 + swz(n, kf*4 + (lane>>4)));
            }
            #pragma unroll
            for (int mf = 0; mf < 2; ++mf)
                #pragma unroll
                for (int nf = 0; nf < 4; ++nf)
                    acc[mf][nf] = __builtin_amdgcn_mfma_f32_16x16x32_f16(
                        a[mf], b[nf], acc[mf][nf], 0, 0, 0);
        }
        __syncthreads();
    }

    int bb = m0 >> 11;          // batch
    int s0 = m0 & (SEQ-1);

    if (z < 2) {
        float sc = (z == 0) ? QSCALE : 1.0f;
        _Float16* out = (_Float16*)(ws + (z==0 ? OFF_Q : OFF_K));
        #pragma unroll
        for (int mf = 0; mf < 2; ++mf)
            #pragma unroll
            for (int nf = 0; nf < 4; ++nf)
                #pragma unroll
                for (int r = 0; r < 4; ++r) {
                    int mrow = w*32 + mf*16 + ((lane>>4)<<2) + r;
                    int col  = nf*16 + (lane & 15);
                    float v = (acc[mf][nf][r] + bias[(z*NH+h)*VD + col]) * sc;
                    out[((bb*NH+h)*SEQ + s0 + mrow)*VD + col] = (_Float16)v;
                }
    } else {
        _Float16* sT = (_Float16*)smem;  // [64][128]
        #pragma unroll
        for (int mf = 0; mf < 2; ++mf)
            #pragma unroll
            for (int nf = 0; nf < 4; ++nf)
                #pragma unroll
                for (int r = 0; r < 4; ++r) {
                    int srow = w*32 + mf*16 + ((lane>>4)<<2) + r;
                    int vd   = nf*16 + (lane & 15);
                    float v = acc[mf][nf][r] + bias[(z*NH+h)*VD + vd];
                    sT[vd*128 + srow] = (_Float16)v;
                }
        __syncthreads();
        _Float16* vt = (_Float16*)(ws + OFF_VT);
        #pragma unroll
        for (int p = 0; p < 4; ++p) {
            int flat = p*256 + tid; int vd = flat >> 4, g = flat & 15;
            uint4 v = *(const uint4*)((char*)sT + vd*256 + g*16);
            *(uint4*)(vt + ((bb*NH+h)*VD + vd)*SEQ + s0 + g*8) = v;
        }
    }
}

// ---------------- kernel 3: flash attention ----------------
// grid (32, 16): (S/64 q-tiles, b*H). block 256 = 4 waves, 16 q-rows/wave.
// KV tile = 128. LDS: K 16K | Vt 16K | P 16K = 48K -> 3 blocks/CU.
__global__ __launch_bounds__(256, 3) void k_attn(char* __restrict__ ws)
{
    __shared__ uint4 smem4[3072];   // 48 KB
    char* smem = (char*)smem4;
    const int OK = 0, OV = 16384, OP = 32768;

    int m0 = blockIdx.x * 64;
    int bh = blockIdx.y;
    int tid = threadIdx.x, lane = tid & 63, w = tid >> 6;

    const _Float16* Qb  = (const _Float16*)(ws + OFF_Q)  + (unsigned)bh*SEQ*VD;
    const _Float16* Kb  = (const _Float16*)(ws + OFF_K)  + (unsigned)bh*SEQ*VD;
    const _Float16* Vtb = (const _Float16*)(ws + OFF_VT) + (unsigned)bh*VD*SEQ;
    _Float16* Zp = (_Float16*)(ws + OFF_Z);

    // Q fragments straight from global (8 KB/block, read once)
    f16x8 aq[2];
    #pragma unroll
    for (int kf = 0; kf < 2; ++kf)
        aq[kf] = *(const f16x8*)(Qb + (m0 + w*16 + (lane & 15))*VD
                                 + kf*32 + (lane>>4)*8);

    float mrun[4], lrun[4];
    f32x4 zacc[4] = {};
    #pragma unroll
    for (int r = 0; r < 4; ++r) { mrun[r] = -INFINITY; lrun[r] = 0.f; }

    for (int t0 = 0; t0 < SEQ; t0 += 128) {
        // stage K [128][64] (swz 128B rows) and Vt [64][128] (swz256)
        #pragma unroll
        for (int p = 0; p < 4; ++p) {
            int flat = p*256 + tid; int r = flat >> 3, g = flat & 7;
            uint4 v = *(const uint4*)(Kb + (t0+r)*VD + g*8);
            *(uint4*)(smem + OK + swz(r, g)) = v;
        }
        #pragma unroll
        for (int p = 0; p < 4; ++p) {
            int flat = p*256 + tid; int r = flat >> 4, g = flat & 15;
            uint4 v = *(const uint4*)(Vtb + r*SEQ + t0 + g*8);
            *(uint4*)(smem + OV + swz256(r, g)) = v;
        }
        __syncthreads();

        // QK^T: sacc[nf] over 128 kv cols (already in exp2 domain)
        f32x4 sacc[8] = {};
        #pragma unroll
        for (int kf = 0; kf < 2; ++kf) {
            f16x8 bk_[8];
            #pragma unroll
            for (int nf = 0; nf < 8; ++nf) {
                int trow = nf*16 + (lane & 15);
                bk_[nf] = *(const f16x8*)(smem + OK + swz(trow, kf*4 + (lane>>4)));
            }
            #pragma unroll
            for (int nf = 0; nf < 8; ++nf)
                sacc[nf] = __builtin_amdgcn_mfma_f32_16x16x32_f16(
                    aq[kf], bk_[nf], sacc[nf], 0, 0, 0);
        }

        // online softmax with defer-max (THR=8 in exp2 domain)
        #pragma unroll
        for (int r = 0; r < 4; ++r) {
            float v = fmaxf(fmaxf(fmaxf(sacc[0][r], sacc[1][r]),
                                  fmaxf(sacc[2][r], sacc[3][r])),
                            fmaxf(fmaxf(sacc[4][r], sacc[5][r]),
                                  fmaxf(sacc[6][r], sacc[7][r])));
            #pragma unroll
            for (int d = 1; d < 16; d <<= 1) v = fmaxf(v, __shfl_xor(v, d, 64));
            if (v > mrun[r] + 8.0f) {
                float al = __builtin_amdgcn_exp2f(mrun[r] - v);
                mrun[r] = v;
                lrun[r] *= al;
                #pragma unroll
                for (int nf = 0; nf < 4; ++nf) zacc[nf][r] *= al;
            }
            float s = 0.f;
            #pragma unroll
            for (int nf = 0; nf < 8; ++nf) {
                float p = __builtin_amdgcn_exp2f(sacc[nf][r] - mrun[r]);
                sacc[nf][r] = p;
                s += p;
            }
            #pragma unroll
            for (int d = 1; d < 16; d <<= 1) s += __shfl_xor(s, d, 64);
            lrun[r] += s;
        }

        // write P (wave-private rows, swz256) — no barrier needed before PV
        #pragma unroll
        for (int nf = 0; nf < 8; ++nf)
            #pragma unroll
            for (int r = 0; r < 4; ++r) {
                int row = w*16 + ((lane>>4)<<2) + r;
                int g   = nf*2 + ((lane>>3) & 1);
                *(_Float16*)(smem + OP + row*256 + ((g ^ (row & 7))<<4)
                             + (lane & 7)*2) = (_Float16)sacc[nf][r];
            }

        // PV: zacc += P[16x128] * Vt^T
        #pragma unroll
        for (int kf = 0; kf < 4; ++kf) {
            int prow = w*16 + (lane & 15);
            f16x8 ap = *(const f16x8*)(smem + OP + swz256(prow, kf*4 + (lane>>4)));
            f16x8 bv_[4];
            #pragma unroll
            for (int nf = 0; nf < 4; ++nf) {
                int vd = nf*16 + (lane & 15);
                bv_[nf] = *(const f16x8*)(smem + OV + swz256(vd, kf*4 + (lane>>4)));
            }
            #pragma unroll
            for (int nf = 0; nf < 4; ++nf)
                zacc[nf] = __builtin_amdgcn_mfma_f32_16x16x32_f16(
                    ap, bv_[nf], zacc[nf], 0, 0, 0);
        }
        __syncthreads();   // protect K/Vt before next tile's staging
    }

    // epilogue: Z[b][s][h*64+vd] f16
    int bb = bh >> 3, h = bh & 7;
    float linv[4];
    #pragma unroll
    for (int r = 0; r < 4; ++r) linv[r] = 1.0f / lrun[r];
    #pragma unroll
    for (int nf = 0; nf < 4; ++nf)
        #pragma unroll
        for (int r = 0; r < 4; ++r) {
            int s  = m0 + w*16 + ((lane>>4)<<2) + r;
            int vd = nf*16 + (lane & 15);
            float v = zacc[nf][r] * linv[r];
            Zp[((unsigned)(bb*SEQ + s))*HID + h*VD + vd] = (_Float16)v;
        }
}

// ---------------- kernel 4: output projection ----------------
__global__ __launch_bounds__(256) void k_outproj(const char* __restrict__ ws,
                                                 const float* __restrict__ bo,
                                                 float* __restrict__ out)
{
    __shared__ uint4 smem4[1536];
    char* smem = (char*)smem4;
    const _Float16* Zp  = (const _Float16*)(ws + OFF_Z);
    const _Float16* wot = (const _Float16*)(ws + OFF_WOT);

    int m0 = blockIdx.x * 128;
    int n0 = blockIdx.y * 64;
    int tid = threadIdx.x, lane = tid & 63, w = tid >> 6;

    f32x4 acc[2][4] = {};

    for (int kt = 0; kt < HID/64; ++kt) {
        #pragma unroll
        for (int p = 0; p < 4; ++p) {
            int flat = p*256 + tid; int row = flat >> 3, g = flat & 7;
            uint4 v = *(const uint4*)(Zp + (m0+row)*HID + kt*64 + g*8);
            *(uint4*)(smem + swz(row, g)) = v;
        }
        #pragma unroll
        for (int p = 0; p < 2; ++p) {
            int flat = p*256 + tid; int n = flat >> 3, g = flat & 7;
            uint4 v = *(const uint4*)(wot + (n0+n)*HID + kt*64 + g*8);
            *(uint4*)(smem + 16384 + swz(n, g)) = v;
        }
        __syncthreads();
        #pragma unroll
        for (int kf = 0; kf < 2; ++kf) {
            f16x8 a[2], b[4];
            #pragma unroll
            for (int mf = 0; mf < 2; ++mf) {
                int row = w*32 + mf*16 + (lane & 15);
                a[mf] = *(const f16x8*)(smem + swz(row, kf*4 + (lane>>4)));
            }
            #pragma unroll
            for (int nf = 0; nf < 4; ++nf) {
                int n = nf*16 + (lane & 15);
                b[nf] = *(const f16x8*)(smem + 16384 + swz(n, kf*4 + (lane>>4)));
            }
            #pragma unroll
            for (int mf = 0; mf < 2; ++mf)
                #pragma unroll
                for (int nf = 0; nf < 4; ++nf)
                    acc[mf][nf] = __builtin_amdgcn_mfma_f32_16x16x32_f16(
                        a[mf], b[nf], acc[mf][nf], 0, 0, 0);
        }
        __syncthreads();
    }

    #pragma unroll
    for (int mf = 0; mf < 2; ++mf)
        #pragma unroll
        for (int nf = 0; nf < 4; ++nf)
            #pragma unroll
            for (int r = 0; r < 4; ++r) {
                int mrow = m0 + w*32 + mf*16 + ((lane>>4)<<2) + r;
                int col  = n0 + nf*16 + (lane & 15);
                out[(unsigned)mrow*HID + col] = acc[mf][nf][r] + bo[col];
            }
}

extern "C" void kernel_launch(void* const* d_in, const int* in_sizes, int n_in,
                              void* d_out, int out_size, void* d_ws, size_t ws_size,
                              hipStream_t stream)
{
    const float* seq = (const float*)d_in[0];
    const float* Wq  = (const float*)d_in[1];
    const float* bq  = (const float*)d_in[2];
    const float* Wk  = (const float*)d_in[3];
    const float* bk  = (const float*)d_in[4];
    const float* Wv  = (const float*)d_in[5];
    const float* bv  = (const float*)d_in[6];
    const float* Wo  = (const float*)d_in[7];
    const float* bo  = (const float*)d_in[8];
    char* ws = (char*)d_ws;
    float* out = (float*)d_out;

    k_convert<<<dim3(512), dim3(256), 0, stream>>>(seq, Wq, bq, Wk, bk, Wv, bv, Wo, ws);
    k_proj<<<dim3(32, 8, 3), dim3(256), 0, stream>>>(ws);
    k_attn<<<dim3(32, 16), dim3(256), 0, stream>>>(ws);
    k_outproj<<<dim3(32, 8), dim3(256), 0, stream>>>(ws, bo, out);
}